// Round 10
// baseline (162.131 us; speedup 1.0000x reference)
//
#include <hip/hip_runtime.h>
#include <hip/hip_bf16.h>

// Problem constants (fixed by the reference's setup_inputs)
#define C_DIM 64
#define P_DIM 16
#define K_DIM 9            // K1*K1
#define PK (P_DIM * K_DIM) // 144
#define INV2S 0.35355339059327373f  // 1/(2*sqrt(2))

// LDS staging row stride for the z epilogue, in halfwords (bf16).
#define ZS_STRIDE 152
// shared buffer: max(64*68*4, 64*152*2) = max(17408, 19456) = 19456 B
#define SH_FLOATS 4864

// ---------------------------------------------------------------------------
// Kernel 1: fused  (a) out[n*16+p] = bias[p] for this block's 64 rows
//                  (b) Zb[n, k*16+p] (bf16) = sum_c x[n,c] * W[p,k,c]
// NOTE layout: Zb is [n][k][p] (k-major) so the edge kernel's 16 p-lanes read
// one contiguous 32B chunk per tap. x tile in LDS; W broadcast from global.
// ---------------------------------------------------------------------------
__global__ __launch_bounds__(256) void z_gemm_kernel(const float* __restrict__ x,
                                                     const float* __restrict__ W,
                                                     const float* __restrict__ bias,
                                                     float* __restrict__ out,
                                                     __hip_bfloat16* __restrict__ Zb,
                                                     int N) {
    __shared__ float sh_raw[SH_FLOATS];
    float (*xs)[C_DIM + 4] = (float(*)[C_DIM + 4])sh_raw;     // [64][68]
    __hip_bfloat16* zs = (__hip_bfloat16*)sh_raw;             // [64 * 152]

    const int block_row = blockIdx.x * 64;
    const int tid = threadIdx.x;

    // (a) bias-init this block's slice of out: 64 rows x 16 = 256 float4s
    {
        const float4 b4 = ((const float4*)bias)[tid & 3];
        const int o4 = block_row * 4 + tid;          // float4 index into out
        if (o4 < N * 4) ((float4*)out)[o4] = b4;
    }

    // stage x tile: 1024 float4s
    for (int i = tid; i < C_DIM * (C_DIM / 4); i += 256) {
        int r = i >> 4, c4 = i & 15;
        int gr = block_row + r;
        float4 v = make_float4(0.0f, 0.0f, 0.0f, 0.0f);
        if (gr < N) v = ((const float4*)x)[(size_t)gr * (C_DIM / 4) + c4];
        *(float4*)&xs[r][c4 * 4] = v;
    }
    __syncthreads();

    const int rg = tid & 15;   // rows rg, rg+16, rg+32, rg+48
    const int p  = tid >> 4;   // 0..15
    const int j0 = p * K_DIM;

    float acc[4][K_DIM];
    #pragma unroll
    for (int i = 0; i < 4; ++i)
        #pragma unroll
        for (int k = 0; k < K_DIM; ++k) acc[i][k] = 0.0f;

    const float4* W4 = (const float4*)W;
    #pragma unroll 4
    for (int cs = 0; cs < 16; ++cs) {
        float4 xv[4];
        #pragma unroll
        for (int i = 0; i < 4; ++i) xv[i] = *(const float4*)&xs[rg + 16 * i][cs * 4];
        #pragma unroll
        for (int k = 0; k < K_DIM; ++k) {
            float4 wv = W4[(size_t)(j0 + k) * (C_DIM / 4) + cs];
            #pragma unroll
            for (int i = 0; i < 4; ++i) {
                acc[i][k] = fmaf(xv[i].x, wv.x, acc[i][k]);
                acc[i][k] = fmaf(xv[i].y, wv.y, acc[i][k]);
                acc[i][k] = fmaf(xv[i].z, wv.z, acc[i][k]);
                acc[i][k] = fmaf(xv[i].w, wv.w, acc[i][k]);
            }
        }
    }
    __syncthreads();   // done reading xs; reuse LDS as zs

    // stage bf16 results in LDS, k-major: zs[row][k*16 + p]
    #pragma unroll
    for (int i = 0; i < 4; ++i) {
        __hip_bfloat16* zrow = &zs[(rg + 16 * i) * ZS_STRIDE];
        #pragma unroll
        for (int k = 0; k < K_DIM; ++k)
            zrow[k * P_DIM + p] = __float2bfloat16(acc[i][k]);
    }
    __syncthreads();

    // coalesced write-out: 64 rows x 18 float4 = 1152 float4s
    const int nrow = min(64, N - block_row);
    float4* Zb4 = (float4*)Zb;
    for (int i = tid; i < nrow * 18; i += 256) {
        int row = i / 18, q = i - row * 18;
        float4 v = *(const float4*)&zs[row * ZS_STRIDE + q * 8];
        Zb4[(size_t)(block_row + row) * 18 + q] = v;
    }
}

// ---------------------------------------------------------------------------
// Kernel 2: edge messages + scatter-add (unsorted), Zb in [n][k][p] layout.
// thread-slot = (eg, p); 16 lanes share an edge; 4 edges per slot.
// ---------------------------------------------------------------------------
#define EILP 4
__global__ __launch_bounds__(256) void edge_kernel(const int* __restrict__ ei,
                                                   const float* __restrict__ pos,
                                                   const float* __restrict__ pose,
                                                   const __hip_bfloat16* __restrict__ Zb,
                                                   float* __restrict__ out,
                                                   int E) {
    const int p  = threadIdx.x & 15;
    const int eg = threadIdx.x >> 4;
    const int e0 = blockIdx.x * (16 * EILP) + eg;

    int  r[EILP], c[EILP];
    bool valid[EILP];
    #pragma unroll
    for (int it = 0; it < EILP; ++it) {
        int e = e0 + it * 16;
        valid[it] = (e < E);
        int ec = valid[it] ? e : 0;
        r[it] = ei[ec];
        c[it] = ei[E + ec];
    }

    float d0[EILP], d1[EILP];
    #pragma unroll
    for (int it = 0; it < EILP; ++it) {
        const float2 pc = ((const float2*)pos)[c[it]];
        const float2 pr = ((const float2*)pos)[r[it]];
        d0[it] = (pc.x - pr.x) * INV2S;
        d1[it] = (pc.y - pr.y) * INV2S;
    }

    float2 ab[EILP];
    #pragma unroll
    for (int it = 0; it < EILP; ++it)
        ab[it] = ((const float2*)pose)[(size_t)r[it] * P_DIM + p];

    #pragma unroll
    for (int it = 0; it < EILP; ++it) {
        const float p0 = fmaf(ab[it].x, d0[it], fmaf(-ab[it].y, d1[it], 0.5f));
        const float p1 = fmaf(ab[it].y, d0[it], fmaf( ab[it].x, d1[it], 0.5f));

        const float v0 = fminf(fmaxf(p0, 0.0f), 1.0f) * 2.0f;
        const float v1 = fminf(fmaxf(p1, 0.0f), 1.0f) * 2.0f;
        const float lo0 = floorf(v0);
        const float lo1 = floorf(v1);
        const float f0 = v0 - lo0;
        const float f1 = v1 - lo1;
        const int i00 = min((int)lo0, 2);
        const int i01 = min((int)lo0 + 1, 2);
        const int i10 = min((int)lo1, 2);
        const int i11 = min((int)lo1 + 1, 2);

        // taps in k-major layout: element (c*9 + t)*16 + p,  t = i0 + 3*i1
        const __hip_bfloat16* __restrict__ Zp = Zb + c[it] * PK + p;
        const int t00 = (i00 + 3 * i10) * P_DIM;
        const int t01 = (i00 + 3 * i11) * P_DIM;
        const int t10 = (i01 + 3 * i10) * P_DIM;
        const int t11 = (i01 + 3 * i11) * P_DIM;

        const float w00 = (1.0f - f0) * (1.0f - f1);
        const float w01 = (1.0f - f0) * f1;
        const float w10 = f0 * (1.0f - f1);
        const float w11 = f0 * f1;

        float m = w00 * __bfloat162float(Zp[t00]);
        m = fmaf(w01, __bfloat162float(Zp[t01]), m);
        m = fmaf(w10, __bfloat162float(Zp[t10]), m);
        m = fmaf(w11, __bfloat162float(Zp[t11]), m);

        if (valid[it]) atomicAdd(&out[(size_t)r[it] * P_DIM + p], m);
    }
}

// ---------------------------------------------------------------------------
extern "C" void kernel_launch(void* const* d_in, const int* in_sizes, int n_in,
                              void* d_out, int out_size, void* d_ws, size_t ws_size,
                              hipStream_t stream) {
    const float* x    = (const float*)d_in[0];
    const float* pos  = (const float*)d_in[1];
    const float* pose = (const float*)d_in[2];
    const float* W    = (const float*)d_in[3];
    const float* bias = (const float*)d_in[4];
    const int*   ei   = (const int*)d_in[5];

    const int N = in_sizes[0] / C_DIM;   // 50000
    const int E = in_sizes[5] / 2;       // 800000

    float* out = (float*)d_out;
    __hip_bfloat16* Zb = (__hip_bfloat16*)d_ws;   // N * 144 bf16 = 14.4 MB

    z_gemm_kernel<<<(N + 63) / 64, 256, 0, stream>>>(x, W, bias, out, Zb, N);
    edge_kernel<<<(E + 16 * EILP - 1) / (16 * EILP), 256, 0, stream>>>(ei, pos, pose, Zb, out, E);
}